// Round 2
// baseline (116.600 us; speedup 1.0000x reference)
//
#include <hip/hip_runtime.h>
#include <hip/hip_bf16.h>

// FourierWeightLinear: out = x @ W + bias, W generated from Fourier features.
// Decomposition:
//   args[i,j,t] = u(i,t) + v(j,t), u = ox*iv + oz*l + phi, v = oy*jv
//   W[i][j] = SCALE * sum_t a_s*sin(u+v) + a_c*cos(u+v)
//           = sum_t P_i[t]*cos(v_j,t) + Q_i[t]*sin(v_j,t)
//   with P = SCALE*(a_s*sin u + a_c*cos u), Q = SCALE*(a_s*cos u - a_c*sin u)
// => W = Ta(1024x192) . Tb(1024x192)^T  (t-interleaved), done as bf16 MFMA GEMM.
// Then out = x @ W as bf16 MFMA GEMM with f32 accumulate + bias.

#define IN_DIM   1024
#define OUT_DIM  1024
#define NBANDS   96
#define KTAB     192          // 2 * NBANDS
#define MX       4096
// SCALE = sqrt(2/(1024+1024)) = 1/32 exactly
#define SCALE_W  0.03125f

typedef __bf16 bf16x8 __attribute__((ext_vector_type(8)));
typedef float  f32x4  __attribute__((ext_vector_type(4)));

#define AS1 __attribute__((address_space(1)))
#define AS3 __attribute__((address_space(3)))

__device__ __forceinline__ void gload_lds16(const void* g, void* l) {
  __builtin_amdgcn_global_load_lds((AS1 void*)(g), (AS3 void*)(l), 16, 0, 0);
}

// ---------------- kernel 0: f32 -> bf16 convert of x ----------------
__global__ void convert_x(const float* __restrict__ x,
                          __hip_bfloat16* __restrict__ xb) {
  int i = (blockIdx.x * 256 + threadIdx.x) * 4;
  float4 v = *(const float4*)(x + i);
  ushort4 o;
  __hip_bfloat16 t;
  t = __float2bfloat16(v.x); o.x = *(unsigned short*)&t;
  t = __float2bfloat16(v.y); o.y = *(unsigned short*)&t;
  t = __float2bfloat16(v.z); o.z = *(unsigned short*)&t;
  t = __float2bfloat16(v.w); o.w = *(unsigned short*)&t;
  *(ushort4*)(xb + i) = o;
}

// ---------------- kernel 1: build Fourier tables ----------------
// Ta[i][2t] = P, Ta[i][2t+1] = Q        (i = in_dim row)
// Tb[j][2t] = cos(v), Tb[j][2t+1] = sin(v)  (j = out_dim col)
__global__ void build_tables(const float* __restrict__ omega,  // [96][3]
                             const float* __restrict__ phi,    // [96]
                             const float* __restrict__ alpha,  // [192]
                             const float* __restrict__ pos,    // [1048576][3]
                             __hip_bfloat16* __restrict__ Ta,
                             __hip_bfloat16* __restrict__ Tb) {
  int idx = blockIdx.x * 256 + threadIdx.x;     // 0 .. 2*1024*96-1
  int half = IN_DIM * NBANDS;
  bool isB = idx >= half;
  int r = isB ? (idx - half) : idx;
  int i = r / NBANDS;
  int t = r - i * NBANDS;
  float lv = pos[2];                            // layer coord (0.5)
  if (!isB) {
    float iv = pos[(size_t)i * OUT_DIM * 3];    // pos[i*1024 + 0].x
    float u = omega[3 * t] * iv + omega[3 * t + 2] * lv + phi[t];
    float su, cu;
    sincosf(u, &su, &cu);
    float as = alpha[t], ac = alpha[NBANDS + t];
    float P = SCALE_W * (as * su + ac * cu);
    float Q = SCALE_W * (as * cu - ac * su);
    Ta[(size_t)i * KTAB + 2 * t]     = __float2bfloat16(P);
    Ta[(size_t)i * KTAB + 2 * t + 1] = __float2bfloat16(Q);
  } else {
    float jv = pos[3 * i + 1];                  // pos[j].y
    float v = omega[3 * t + 1] * jv;
    float sv, cv;
    sincosf(v, &sv, &cv);
    Tb[(size_t)i * KTAB + 2 * t]     = __float2bfloat16(cv);
    Tb[(size_t)i * KTAB + 2 * t + 1] = __float2bfloat16(sv);
  }
}

// ---------------- GEMM: C[M][N] = A[M][K] . B[N][K]^T ----------------
// m97-style: 128x128 tile, 4 waves (2x2), BK=32, 16x16x32 bf16 MFMA,
// global_load_lds width-16 staging.
template <int OUT_BF16>
__global__ __launch_bounds__(256)
void gemm_bt(const __hip_bfloat16* __restrict__ A,
             const __hip_bfloat16* __restrict__ B,
             void* __restrict__ Cout,
             const float* __restrict__ bias,
             int M, int N, int K) {
  __shared__ __align__(16) __hip_bfloat16 As[128 * 32];
  __shared__ __align__(16) __hip_bfloat16 Bs[128 * 32];
  const int tid  = threadIdx.x;
  const int lane = tid & 63;
  const int wave = tid >> 6;
  const int wr = wave >> 1, wc = wave & 1;   // 2x2 waves, each 64x64
  const int m0 = blockIdx.y * 128;
  const int n0 = blockIdx.x * 128;

  f32x4 acc[4][4] = {};

  const int lr = lane & 15;          // row within 16x16 frag (A-m / B-n)
  const int lk = (lane >> 4) * 8;    // k offset of the 8 contiguous elems

  for (int k0 = 0; k0 < K; k0 += 32) {
    // stage A and B 128x32 tiles; 512 16B-chunks each, 256 threads x 2
#pragma unroll
    for (int q = 0; q < 2; ++q) {
      int f = q * 256 + tid;         // 16B-chunk index 0..511
      int r = f >> 2;                // tile row 0..127 (64B per row)
      int c16 = f & 3;               // which 16B within the row
      gload_lds16(A + (size_t)(m0 + r) * K + k0 + c16 * 8,
                  (char*)As + (size_t)f * 16);
      gload_lds16(B + (size_t)(n0 + r) * K + k0 + c16 * 8,
                  (char*)Bs + (size_t)f * 16);
    }
    __syncthreads();

    bf16x8 af[4], bfr[4];
#pragma unroll
    for (int mi = 0; mi < 4; ++mi)
      af[mi] = *(const bf16x8*)&As[(wr * 64 + mi * 16 + lr) * 32 + lk];
#pragma unroll
    for (int ni = 0; ni < 4; ++ni)
      bfr[ni] = *(const bf16x8*)&Bs[(wc * 64 + ni * 16 + lr) * 32 + lk];
#pragma unroll
    for (int mi = 0; mi < 4; ++mi)
#pragma unroll
      for (int ni = 0; ni < 4; ++ni)
        acc[mi][ni] = __builtin_amdgcn_mfma_f32_16x16x32_bf16(
            af[mi], bfr[ni], acc[mi][ni], 0, 0, 0);
    __syncthreads();
  }

  // epilogue: D row = (lane>>4)*4 + reg, col = lane&15 (m89/m91 layout)
#pragma unroll
  for (int mi = 0; mi < 4; ++mi) {
#pragma unroll
    for (int ni = 0; ni < 4; ++ni) {
#pragma unroll
      for (int r = 0; r < 4; ++r) {
        int row = m0 + wr * 64 + mi * 16 + (lane >> 4) * 4 + r;
        int col = n0 + wc * 64 + ni * 16 + lr;
        float v = acc[mi][ni][r];
        if (OUT_BF16) {
          ((__hip_bfloat16*)Cout)[(size_t)row * N + col] = __float2bfloat16(v);
        } else {
          ((float*)Cout)[(size_t)row * N + col] = v + bias[col];
        }
      }
    }
  }
}

extern "C" void kernel_launch(void* const* d_in, const int* in_sizes, int n_in,
                              void* d_out, int out_size, void* d_ws, size_t ws_size,
                              hipStream_t stream) {
  const float* x     = (const float*)d_in[0];   // [4096][1024] f32
  const float* omega = (const float*)d_in[1];   // [96][3]
  const float* phi   = (const float*)d_in[2];   // [96]
  const float* alpha = (const float*)d_in[3];   // [192]
  const float* bias  = (const float*)d_in[4];   // [1024]
  const float* pos   = (const float*)d_in[5];   // [1048576][3]
  float* out = (float*)d_out;                   // [4096][1024] f32
  (void)in_sizes; (void)n_in; (void)out_size; (void)ws_size;

  // workspace layout
  char* ws = (char*)d_ws;
  __hip_bfloat16* Xb = (__hip_bfloat16*)(ws);                  // 8 MiB
  __hip_bfloat16* WT = (__hip_bfloat16*)(ws + 8388608);        // 2 MiB  WT[n][i]
  __hip_bfloat16* Ta = (__hip_bfloat16*)(ws + 10485760);       // 384 KiB
  __hip_bfloat16* Tb = (__hip_bfloat16*)(ws + 10878976);       // 384 KiB

  // 0) x -> bf16
  convert_x<<<dim3((MX * IN_DIM) / (256 * 4)), dim3(256), 0, stream>>>(x, Xb);
  // 1) Fourier tables (2*1024*96 work items)
  build_tables<<<dim3((2 * IN_DIM * NBANDS) / 256), dim3(256), 0, stream>>>(
      omega, phi, alpha, pos, Ta, Tb);
  // 2) WT[n][i] = sum_t Tb[n][t] * Ta[i][t]   (M=1024, N=1024, K=192)
  gemm_bt<1><<<dim3(OUT_DIM / 128, IN_DIM / 128), dim3(256), 0, stream>>>(
      Tb, Ta, (void*)WT, nullptr, IN_DIM, OUT_DIM, KTAB);
  // 3) out[m][j] = sum_i Xb[m][i] * WT[j][i] + bias[j]
  gemm_bt<0><<<dim3(OUT_DIM / 128, MX / 128), dim3(256), 0, stream>>>(
      Xb, WT, (void*)out, bias, MX, OUT_DIM, IN_DIM);
}

// Round 3
// 102.362 us; speedup vs baseline: 1.1391x; 1.1391x over previous
//
#include <hip/hip_runtime.h>
#include <hip/hip_bf16.h>
#include <math.h>

// FourierWeightLinear: out = x @ W + bias, W = Ta(1024x192) . Tb(1024x192)^T.
// Associativity: out = (x @ Ta) @ Tb^T  -- never materialize W.
//   Ta[i][2t]=P(i,t), Ta[i][2t+1]=Q(i,t)   (stored transposed: TaT[192][1024])
//   Tb[j][2t]=cos(oy_t*jv), Tb[j][2t+1]=sin(oy_t*jv)
//   P = SCALE*(a_s*sin u + a_c*cos u), Q = SCALE*(a_s*cos u - a_c*sin u)
//   u = ox*iv + oz*0.5 + phi;  iv(i)=jv(i)=(i+1)/1025 (exact f32 match to ref)
// G1: Y[4096][192] = x @ Ta   (K=1024, split-K=4, fused f32->bf16 of x)
// G2: out[4096][1024] = Y @ Tb^T + bias  (K=192)

#define IN_DIM   1024
#define OUT_DIM  1024
#define NBANDS   96
#define KTAB     192
#define MX       4096
#define SCALE_W  0.03125f
#define NSPLIT   4

typedef __bf16 bf16x8 __attribute__((ext_vector_type(8)));
typedef float  f32x4  __attribute__((ext_vector_type(4)));

#define AS1 __attribute__((address_space(1)))
#define AS3 __attribute__((address_space(3)))

__device__ __forceinline__ void gload_lds16(const void* g, void* l) {
  __builtin_amdgcn_global_load_lds((AS1 void*)(g), (AS3 void*)(l), 16, 0, 0);
}

__device__ __forceinline__ unsigned short bf16bits(float f) {
  __hip_bfloat16 b = __float2bfloat16(f);
  return *(unsigned short*)&b;
}

// ---------------- kernel 1: build Fourier tables (no pos reads) ----------
// one block per band t (96 blocks); coalesced TaT rows, strided Tb writes.
__global__ void build_tables(const float* __restrict__ omega,  // [96][3]
                             const float* __restrict__ phi,    // [96]
                             const float* __restrict__ alpha,  // [192]
                             __hip_bfloat16* __restrict__ TaT, // [192][1024]
                             __hip_bfloat16* __restrict__ Tb) {// [1024][192]
  const int t = blockIdx.x;
  const float ox = omega[3 * t], oy = omega[3 * t + 1], oz = omega[3 * t + 2];
  const float uc = oz * 0.5f + phi[t];
  const float as_ = alpha[t], ac = alpha[NBANDS + t];
#pragma unroll
  for (int s = 0; s < 4; ++s) {
    const int i = s * 256 + threadIdx.x;            // 0..1023
    const float coord = (float)(i + 1) / 1025.0f;   // == pos coords exactly
    float su, cu;
    sincosf(ox * coord + uc, &su, &cu);
    const float P = SCALE_W * (as_ * su + ac * cu);
    const float Q = SCALE_W * (as_ * cu - ac * su);
    TaT[(size_t)(2 * t) * IN_DIM + i]     = __float2bfloat16(P);
    TaT[(size_t)(2 * t + 1) * IN_DIM + i] = __float2bfloat16(Q);
    float sv, cv;
    sincosf(oy * coord, &sv, &cv);
    Tb[(size_t)i * KTAB + 2 * t]     = __float2bfloat16(cv);
    Tb[(size_t)i * KTAB + 2 * t + 1] = __float2bfloat16(sv);
  }
}

// ---------------- G1: Y partials = x(f32) @ Ta, split-K ------------------
// BM=64, BN=192 (all of N), 8 waves (2m x 4n), per-wave 32x48 = acc[2][3].
// grid (1, 64, 4); K-chunk 256 per split, BK=32.
__global__ __launch_bounds__(512)
void gemm_xta(const float* __restrict__ X,             // [4096][1024] f32
              const __hip_bfloat16* __restrict__ TaT,  // [192][1024]
              float* __restrict__ Pp) {                // [4][4096][192] f32
  __shared__ __align__(16) __hip_bfloat16 As[64 * 32];
  __shared__ __align__(16) __hip_bfloat16 Bs[192 * 32];
  const int tid  = threadIdx.x;
  const int lane = tid & 63;
  const int wave = tid >> 6;          // 0..7
  const int wr = wave >> 2;           // 0..1 -> rows 32*wr
  const int wc = wave & 3;            // 0..3 -> cols 48*wc
  const int m0  = blockIdx.y * 64;
  const int ks0 = blockIdx.z * (IN_DIM / NSPLIT);   // 256-wide K chunk

  f32x4 acc[2][3] = {};
  const int lr = lane & 15;
  const int lk = (lane >> 4) * 8;

  for (int k0 = 0; k0 < IN_DIM / NSPLIT; k0 += 32) {
    // A: 64x32 f32 -> bf16, reg-staged (fused convert). 512 float4, 1/thread.
    {
      const int r = tid >> 3;          // 8 float4 per 32-f32 row
      const int c4 = tid & 7;
      float4 v = *(const float4*)(X + (size_t)(m0 + r) * IN_DIM + ks0 + k0 + c4 * 4);
      ushort4 o;
      o.x = bf16bits(v.x); o.y = bf16bits(v.y);
      o.z = bf16bits(v.z); o.w = bf16bits(v.w);
      *(ushort4*)((char*)As + (size_t)r * 64 + c4 * 8) = o;
    }
    // B: 192x32 bf16 via global_load_lds, 768 16B-chunks.
    {
      const int r = tid >> 2, c16 = tid & 3;
      gload_lds16(TaT + (size_t)r * IN_DIM + ks0 + k0 + c16 * 8,
                  (char*)Bs + (size_t)tid * 16);
      if (tid < 256) {                 // waves 0-3, wave-uniform branch
        const int c2 = 512 + tid;
        const int r2 = c2 >> 2, c162 = c2 & 3;
        gload_lds16(TaT + (size_t)r2 * IN_DIM + ks0 + k0 + c162 * 8,
                    (char*)Bs + (size_t)c2 * 16);
      }
    }
    __syncthreads();

    bf16x8 af[2], bfr[3];
#pragma unroll
    for (int mi = 0; mi < 2; ++mi)
      af[mi] = *(const bf16x8*)&As[(wr * 32 + mi * 16 + lr) * 32 + lk];
#pragma unroll
    for (int ni = 0; ni < 3; ++ni)
      bfr[ni] = *(const bf16x8*)&Bs[(wc * 48 + ni * 16 + lr) * 32 + lk];
#pragma unroll
    for (int mi = 0; mi < 2; ++mi)
#pragma unroll
      for (int ni = 0; ni < 3; ++ni)
        acc[mi][ni] = __builtin_amdgcn_mfma_f32_16x16x32_bf16(
            af[mi], bfr[ni], acc[mi][ni], 0, 0, 0);
    __syncthreads();
  }

  float* P = Pp + (size_t)blockIdx.z * (MX * KTAB);
#pragma unroll
  for (int mi = 0; mi < 2; ++mi)
#pragma unroll
    for (int ni = 0; ni < 3; ++ni)
#pragma unroll
      for (int r = 0; r < 4; ++r) {
        const int row = m0 + wr * 32 + mi * 16 + (lane >> 4) * 4 + r;
        const int col = wc * 48 + ni * 16 + lr;
        P[(size_t)row * KTAB + col] = acc[mi][ni][r];
      }
}

// ---------------- reduce partials -> Y bf16 ------------------------------
__global__ void reduce_y(const float* __restrict__ Pp,
                         __hip_bfloat16* __restrict__ Y) {
  const int i = (blockIdx.x * 256 + threadIdx.x) * 4;
  const int S = MX * KTAB;
  float4 a = *(const float4*)(Pp + i);
  float4 b = *(const float4*)(Pp + S + i);
  float4 c = *(const float4*)(Pp + 2 * S + i);
  float4 d = *(const float4*)(Pp + 3 * S + i);
  ushort4 o;
  o.x = bf16bits(a.x + b.x + c.x + d.x);
  o.y = bf16bits(a.y + b.y + c.y + d.y);
  o.z = bf16bits(a.z + b.z + c.z + d.z);
  o.w = bf16bits(a.w + b.w + c.w + d.w);
  *(ushort4*)(Y + i) = o;
}

// ---------------- G2: out = Y @ Tb^T + bias ------------------------------
// BM=64, BN=128, 4 waves (2x2), per-wave 32x64 = acc[2][4]. grid (8, 64).
__global__ __launch_bounds__(256)
void gemm_out(const __hip_bfloat16* __restrict__ Y,   // [4096][192]
              const __hip_bfloat16* __restrict__ Tb,  // [1024][192]
              float* __restrict__ out,                // [4096][1024]
              const float* __restrict__ bias) {       // [1024]
  __shared__ __align__(16) __hip_bfloat16 As[64 * 32];
  __shared__ __align__(16) __hip_bfloat16 Bs[128 * 32];
  const int tid  = threadIdx.x;
  const int lane = tid & 63;
  const int wave = tid >> 6;
  const int wr = wave >> 1;          // 0..1 -> rows 32*wr
  const int wc = wave & 1;           // 0..1 -> cols 64*wc
  const int m0 = blockIdx.y * 64;
  const int n0 = blockIdx.x * 128;

  f32x4 acc[2][4] = {};
  const int lr = lane & 15;
  const int lk = (lane >> 4) * 8;

  for (int k0 = 0; k0 < KTAB; k0 += 32) {
    // A: 64x32 = 256 chunks, 1/thread
    {
      const int r = tid >> 2, c16 = tid & 3;
      gload_lds16(Y + (size_t)(m0 + r) * KTAB + k0 + c16 * 8,
                  (char*)As + (size_t)tid * 16);
    }
    // B: 128x32 = 512 chunks, 2/thread
#pragma unroll
    for (int q = 0; q < 2; ++q) {
      const int f = q * 256 + tid;
      const int r = f >> 2, c16 = f & 3;
      gload_lds16(Tb + (size_t)(n0 + r) * KTAB + k0 + c16 * 8,
                  (char*)Bs + (size_t)f * 16);
    }
    __syncthreads();

    bf16x8 af[2], bfr[4];
#pragma unroll
    for (int mi = 0; mi < 2; ++mi)
      af[mi] = *(const bf16x8*)&As[(wr * 32 + mi * 16 + lr) * 32 + lk];
#pragma unroll
    for (int ni = 0; ni < 4; ++ni)
      bfr[ni] = *(const bf16x8*)&Bs[(wc * 64 + ni * 16 + lr) * 32 + lk];
#pragma unroll
    for (int mi = 0; mi < 2; ++mi)
#pragma unroll
      for (int ni = 0; ni < 4; ++ni)
        acc[mi][ni] = __builtin_amdgcn_mfma_f32_16x16x32_bf16(
            af[mi], bfr[ni], acc[mi][ni], 0, 0, 0);
    __syncthreads();
  }

#pragma unroll
  for (int mi = 0; mi < 2; ++mi)
#pragma unroll
    for (int ni = 0; ni < 4; ++ni)
#pragma unroll
      for (int r = 0; r < 4; ++r) {
        const int row = m0 + wr * 32 + mi * 16 + (lane >> 4) * 4 + r;
        const int col = n0 + wc * 64 + ni * 16 + lr;
        out[(size_t)row * OUT_DIM + col] = acc[mi][ni][r] + bias[col];
      }
}

extern "C" void kernel_launch(void* const* d_in, const int* in_sizes, int n_in,
                              void* d_out, int out_size, void* d_ws, size_t ws_size,
                              hipStream_t stream) {
  const float* x     = (const float*)d_in[0];   // [4096][1024] f32
  const float* omega = (const float*)d_in[1];   // [96][3]
  const float* phi   = (const float*)d_in[2];   // [96]
  const float* alpha = (const float*)d_in[3];   // [192]
  const float* bias  = (const float*)d_in[4];   // [1024]
  float* out = (float*)d_out;                   // [4096][1024] f32
  (void)in_sizes; (void)n_in; (void)out_size; (void)ws_size;

  // workspace layout
  char* ws = (char*)d_ws;
  float* Pp           = (float*)(ws);                         // 4*3MiB = 12 MiB
  __hip_bfloat16* Y   = (__hip_bfloat16*)(ws + 12582912);     // 1.5 MiB
  __hip_bfloat16* TaT = (__hip_bfloat16*)(ws + 14155776);     // 384 KiB
  __hip_bfloat16* Tb  = (__hip_bfloat16*)(ws + 14548992);     // 384 KiB

  // 1) Fourier tables (96 blocks, one per band)
  build_tables<<<dim3(NBANDS), dim3(256), 0, stream>>>(omega, phi, alpha, TaT, Tb);
  // 2) Y partials = x @ Ta  (fused f32->bf16 of x; split-K=4)
  gemm_xta<<<dim3(1, MX / 64, NSPLIT), dim3(512), 0, stream>>>(x, TaT, Pp);
  // 3) Y = sum partials -> bf16
  reduce_y<<<dim3((MX * KTAB) / (256 * 4)), dim3(256), 0, stream>>>(Pp, Y);
  // 4) out = Y @ Tb^T + bias
  gemm_out<<<dim3(OUT_DIM / 128, MX / 64), dim3(256), 0, stream>>>(Y, Tb, out, bias);
}

// Round 4
// 99.034 us; speedup vs baseline: 1.1774x; 1.0336x over previous
//
#include <hip/hip_runtime.h>
#include <hip/hip_bf16.h>
#include <math.h>

// FourierWeightLinear: out = x @ W + bias, W = Ta(1024x192) . Tb(1024x192)^T.
// Associativity: out = (x @ Ta) @ Tb^T  -- never materialize W.
//   u = ox*iv + oz*0.5 + phi;  iv(i)=jv(i)=(i+1)/1025 (exact f32 match to ref)
//   TaT[2t][i]=P, TaT[2t+1][i]=Q;  Tb[j][2t]=cos(oy*jv), Tb[j][2t+1]=sin(oy*jv)
// G1: Pp[z] = x(chunk z) @ Ta   (split-K=4, fused f32->bf16, 2-phase dbuf)
// reduce: Y = sum_z Pp[z] -> bf16
// G2: out = Y @ Tb^T + bias     (K=192, 2-phase dbuf)

#define IN_DIM   1024
#define OUT_DIM  1024
#define NBANDS   96
#define KTAB     192
#define MX       4096
#define SCALE_W  0.03125f
#define NSPLIT   4

typedef __bf16 bf16x8 __attribute__((ext_vector_type(8)));
typedef float  f32x4  __attribute__((ext_vector_type(4)));

#define AS1 __attribute__((address_space(1)))
#define AS3 __attribute__((address_space(3)))

__device__ __forceinline__ void gload_lds16(const void* g, void* l) {
  __builtin_amdgcn_global_load_lds((AS1 void*)(g), (AS3 void*)(l), 16, 0, 0);
}

__device__ __forceinline__ unsigned short bf16bits(float f) {
  __hip_bfloat16 b = __float2bfloat16(f);
  return *(unsigned short*)&b;
}

// ---------------- tables: 384 blocks (96 bands x 4 row-chunks) -----------
__global__ void build_tables(const float* __restrict__ omega,  // [96][3]
                             const float* __restrict__ phi,    // [96]
                             const float* __restrict__ alpha,  // [192]
                             __hip_bfloat16* __restrict__ TaT, // [192][1024]
                             __hip_bfloat16* __restrict__ Tb) {// [1024][192]
  const int t = blockIdx.x;
  const int i = blockIdx.y * 256 + threadIdx.x;     // 0..1023
  const float ox = omega[3 * t], oy = omega[3 * t + 1], oz = omega[3 * t + 2];
  const float uc = oz * 0.5f + phi[t];
  const float as_ = alpha[t], ac = alpha[NBANDS + t];
  const float coord = (float)(i + 1) / 1025.0f;     // == pos coords exactly
  float su, cu;
  sincosf(ox * coord + uc, &su, &cu);
  TaT[(size_t)(2 * t) * IN_DIM + i]     = __float2bfloat16(SCALE_W * (as_ * su + ac * cu));
  TaT[(size_t)(2 * t + 1) * IN_DIM + i] = __float2bfloat16(SCALE_W * (as_ * cu - ac * su));
  float sv, cv;
  sincosf(oy * coord, &sv, &cv);
  Tb[(size_t)i * KTAB + 2 * t]     = __float2bfloat16(cv);
  Tb[(size_t)i * KTAB + 2 * t + 1] = __float2bfloat16(sv);
}

// ---------------- G1: Pp = x @ Ta, split-K=4, BM=32, BK=64, dbuf ---------
// grid (1, 128, 4), 256 threads (4 waves, each 32x48 = acc[2][3]).
__global__ __launch_bounds__(256)
void gemm_xta(const float* __restrict__ X,             // [4096][1024] f32
              const __hip_bfloat16* __restrict__ TaT,  // [192][1024]
              float* __restrict__ Pp) {                // [4][4096][192] f32
  __shared__ __align__(16) __hip_bfloat16 As[2][32 * 64];
  __shared__ __align__(16) __hip_bfloat16 Bs[2][192 * 64];
  const int tid  = threadIdx.x;
  const int lane = tid & 63;
  const int wc   = tid >> 6;                       // wave -> col block (48)
  const int m0   = blockIdx.y * 32;
  const int ks0  = blockIdx.z * (IN_DIM / NSPLIT); // 256-wide K chunk
  const int lr = lane & 15;
  const int lk = (lane >> 4) * 8;

  const float* xbase = X + (size_t)m0 * IN_DIM + ks0;
  const __hip_bfloat16* bbase = TaT + ks0;

  f32x4 acc[2][3] = {};

  auto ALOAD = [&](int t, float4* a) {
#pragma unroll
    for (int q = 0; q < 2; ++q) {
      const int f = q * 256 + tid;
      const int r = f >> 4, c4 = f & 15;           // 16 float4 per 64-col row
      a[q] = *(const float4*)(xbase + (size_t)r * IN_DIM + t * 64 + c4 * 4);
    }
  };
  auto AWRITE = [&](int buf, const float4* a) {
#pragma unroll
    for (int q = 0; q < 2; ++q) {
      const int f = q * 256 + tid;
      const int r = f >> 4, c4 = f & 15;
      ushort4 o;
      o.x = bf16bits(a[q].x); o.y = bf16bits(a[q].y);
      o.z = bf16bits(a[q].z); o.w = bf16bits(a[q].w);
      *(ushort4*)((char*)&As[buf][0] + r * 128 + c4 * 8) = o;
    }
  };
  auto BSTAGE = [&](int t, int buf) {
#pragma unroll
    for (int q = 0; q < 6; ++q) {
      const int f = q * 256 + tid;                 // 1536 16B chunks
      const int r = f >> 3, g = f & 7;             // 8 chunks per 128B row
      gload_lds16(bbase + (size_t)r * IN_DIM + t * 64 + g * 8,
                  (char*)&Bs[buf][0] + (size_t)f * 16);
    }
  };
  auto COMPUTE = [&](int buf) {
#pragma unroll
    for (int kk = 0; kk < 2; ++kk) {
      bf16x8 af[2], bfr[3];
#pragma unroll
      for (int mi = 0; mi < 2; ++mi)
        af[mi] = *(const bf16x8*)&As[buf][(mi * 16 + lr) * 64 + kk * 32 + lk];
#pragma unroll
      for (int ni = 0; ni < 3; ++ni)
        bfr[ni] = *(const bf16x8*)&Bs[buf][(wc * 48 + ni * 16 + lr) * 64 + kk * 32 + lk];
#pragma unroll
      for (int mi = 0; mi < 2; ++mi)
#pragma unroll
        for (int ni = 0; ni < 3; ++ni)
          acc[mi][ni] = __builtin_amdgcn_mfma_f32_16x16x32_bf16(
              af[mi], bfr[ni], acc[mi][ni], 0, 0, 0);
    }
  };

  float4 a0[2];
  ALOAD(0, a0); BSTAGE(0, 0); AWRITE(0, a0);
  __syncthreads();
#pragma unroll
  for (int t = 0; t < 4; ++t) {
    const int cur = t & 1;
    float4 an[2];
    if (t < 3) { ALOAD(t + 1, an); BSTAGE(t + 1, cur ^ 1); }
    COMPUTE(cur);
    if (t < 3) AWRITE(cur ^ 1, an);
    __syncthreads();
  }

  float* P = Pp + (size_t)blockIdx.z * (MX * KTAB);
#pragma unroll
  for (int mi = 0; mi < 2; ++mi)
#pragma unroll
    for (int ni = 0; ni < 3; ++ni)
#pragma unroll
      for (int r = 0; r < 4; ++r) {
        const int row = m0 + mi * 16 + (lane >> 4) * 4 + r;
        const int col = wc * 48 + ni * 16 + lr;
        P[(size_t)row * KTAB + col] = acc[mi][ni][r];
      }
}

// ---------------- reduce partials -> Y bf16 ------------------------------
__global__ void reduce_y(const float* __restrict__ Pp,
                         __hip_bfloat16* __restrict__ Y) {
  const int i = (blockIdx.x * 256 + threadIdx.x) * 4;
  const int S = MX * KTAB;
  float4 a = *(const float4*)(Pp + i);
  float4 b = *(const float4*)(Pp + S + i);
  float4 c = *(const float4*)(Pp + 2 * S + i);
  float4 d = *(const float4*)(Pp + 3 * S + i);
  ushort4 o;
  o.x = bf16bits(a.x + b.x + c.x + d.x);
  o.y = bf16bits(a.y + b.y + c.y + d.y);
  o.z = bf16bits(a.z + b.z + c.z + d.z);
  o.w = bf16bits(a.w + b.w + c.w + d.w);
  *(ushort4*)(Y + i) = o;
}

// ---------------- G2: out = Y @ Tb^T + bias, BK=64, dbuf -----------------
// grid (8, 64), 256 threads (2x2 waves, each 32x64 = acc[2][4]).
__global__ __launch_bounds__(256)
void gemm_out(const __hip_bfloat16* __restrict__ Y,   // [4096][192]
              const __hip_bfloat16* __restrict__ Tb,  // [1024][192]
              float* __restrict__ out,                // [4096][1024]
              const float* __restrict__ bias) {       // [1024]
  __shared__ __align__(16) __hip_bfloat16 As[2][64 * 64];
  __shared__ __align__(16) __hip_bfloat16 Bs[2][128 * 64];
  const int tid  = threadIdx.x;
  const int lane = tid & 63;
  const int wave = tid >> 6;
  const int wr = wave >> 1;
  const int wc = wave & 1;
  const int m0 = blockIdx.y * 64;
  const int n0 = blockIdx.x * 128;
  const int lr = lane & 15;
  const int lk = (lane >> 4) * 8;

  f32x4 acc[2][4] = {};

  auto ASTAGE = [&](int t, int buf) {
#pragma unroll
    for (int q = 0; q < 2; ++q) {
      const int f = q * 256 + tid;                 // 512 chunks (64x64 bf16)
      const int r = f >> 3, g = f & 7;
      gload_lds16(Y + (size_t)(m0 + r) * KTAB + t * 64 + g * 8,
                  (char*)&As[buf][0] + (size_t)f * 16);
    }
  };
  auto BSTAGE = [&](int t, int buf) {
#pragma unroll
    for (int q = 0; q < 4; ++q) {
      const int f = q * 256 + tid;                 // 1024 chunks (128x64)
      const int r = f >> 3, g = f & 7;
      gload_lds16(Tb + (size_t)(n0 + r) * KTAB + t * 64 + g * 8,
                  (char*)&Bs[buf][0] + (size_t)f * 16);
    }
  };
  auto COMPUTE = [&](int buf) {
#pragma unroll
    for (int kk = 0; kk < 2; ++kk) {
      bf16x8 af[2], bfr[4];
#pragma unroll
      for (int mi = 0; mi < 2; ++mi)
        af[mi] = *(const bf16x8*)&As[buf][(wr * 32 + mi * 16 + lr) * 64 + kk * 32 + lk];
#pragma unroll
      for (int ni = 0; ni < 4; ++ni)
        bfr[ni] = *(const bf16x8*)&Bs[buf][(wc * 64 + ni * 16 + lr) * 64 + kk * 32 + lk];
#pragma unroll
      for (int mi = 0; mi < 2; ++mi)
#pragma unroll
        for (int ni = 0; ni < 4; ++ni)
          acc[mi][ni] = __builtin_amdgcn_mfma_f32_16x16x32_bf16(
              af[mi], bfr[ni], acc[mi][ni], 0, 0, 0);
    }
  };

  ASTAGE(0, 0); BSTAGE(0, 0);
  __syncthreads();
#pragma unroll
  for (int t = 0; t < 3; ++t) {
    const int cur = t & 1;
    if (t < 2) { ASTAGE(t + 1, cur ^ 1); BSTAGE(t + 1, cur ^ 1); }
    COMPUTE(cur);
    __syncthreads();
  }

#pragma unroll
  for (int mi = 0; mi < 2; ++mi)
#pragma unroll
    for (int ni = 0; ni < 4; ++ni)
#pragma unroll
      for (int r = 0; r < 4; ++r) {
        const int row = m0 + wr * 32 + mi * 16 + (lane >> 4) * 4 + r;
        const int col = n0 + wc * 64 + ni * 16 + lr;
        out[(size_t)row * OUT_DIM + col] = acc[mi][ni][r] + bias[col];
      }
}

extern "C" void kernel_launch(void* const* d_in, const int* in_sizes, int n_in,
                              void* d_out, int out_size, void* d_ws, size_t ws_size,
                              hipStream_t stream) {
  const float* x     = (const float*)d_in[0];   // [4096][1024] f32
  const float* omega = (const float*)d_in[1];   // [96][3]
  const float* phi   = (const float*)d_in[2];   // [96]
  const float* alpha = (const float*)d_in[3];   // [192]
  const float* bias  = (const float*)d_in[4];   // [1024]
  float* out = (float*)d_out;                   // [4096][1024] f32
  (void)in_sizes; (void)n_in; (void)out_size; (void)ws_size;

  char* ws = (char*)d_ws;
  float* Pp           = (float*)(ws);                         // 12 MiB
  __hip_bfloat16* Y   = (__hip_bfloat16*)(ws + 12582912);     // 1.5 MiB
  __hip_bfloat16* TaT = (__hip_bfloat16*)(ws + 14155776);     // 384 KiB
  __hip_bfloat16* Tb  = (__hip_bfloat16*)(ws + 14548992);     // 384 KiB

  build_tables<<<dim3(NBANDS, 4), dim3(256), 0, stream>>>(omega, phi, alpha, TaT, Tb);
  gemm_xta<<<dim3(1, MX / 32, NSPLIT), dim3(256), 0, stream>>>(x, TaT, Pp);
  reduce_y<<<dim3((MX * KTAB) / (256 * 4)), dim3(256), 0, stream>>>(Pp, Y);
  gemm_out<<<dim3(OUT_DIM / 128, MX / 64), dim3(256), 0, stream>>>(Y, Tb, out, bias);
}